// Round 3
// baseline (1380.217 us; speedup 1.0000x reference)
//
#include <hip/hip_runtime.h>

// CRF NLL forward loss. B=256, T=2048, K2=52 (50 labels + START=50 + STOP=51).
// Linear-domain forward recurrence, one wave per batch, no LDS, no barriers,
// and NO per-step max-reduction: renormalize by the (always-positive) value of
// reference lane 50 (START). Ratios of state entries are bounded by the
// transition-matrix range (~2^12), so single-lane renorm keeps v in ~2^+-20.
//   v_{t+1}[n] = E_t[n] * (sum_p M2[n][p] v_t[p]) * rcp(v_t[50])
//   C += log2(v_t[50]);  alpha_t = v_t * 2^C
// Per-step chain is issue-bound (~240 cyc): 52 v_readlane + 52 v_fmac + 3 transc.

#define B_    256
#define T_    2048
#define K2_   52
#define PF    8
#define LOG2E_ 1.4426950408889634f
#define LN2_   0.6931471805599453f

__device__ __forceinline__ float rdlane(float v, int src) {
  return __uint_as_float(__builtin_amdgcn_readlane(__float_as_uint(v), src));
}

__launch_bounds__(64, 1)
__global__ void crf_fwd_kernel(const float* __restrict__ em,
                               const float* __restrict__ tr,
                               const int*  __restrict__ len,
                               const int*  __restrict__ lab,
                               float* __restrict__ per_b)
{
  const int b    = blockIdx.x;
  const int lane = threadIdx.x;                      // 64
  const int n    = (lane < K2_) ? lane : (K2_ - 1);  // lanes 52..63 mirror lane 51
  const int L    = len[b];
  const float* emb = em + (size_t)b * (T_ * K2_);

  // Row n of exp2-transitions, resident in VGPRs.
  float M2[K2_];
#pragma unroll
  for (int p = 0; p < K2_; ++p)
    M2[p] = __builtin_amdgcn_exp2f(tr[n * K2_ + p] * LOG2E_);

  // linear-domain state; alpha = v * 2^C.  v starts as delta at START.
  float v = (lane == K2_ - 2) ? 1.0f : 0.0f;
  float C = 0.0f;

  // emission prefetch ring (rows t..t+PF-1); ~8 steps of latency slack
  float pf[PF];
#pragma unroll
  for (int i = 0; i < PF; ++i)
    pf[i] = emb[i * K2_ + n];

  for (int t = 0; t < L; ++t) {
    float emv = pf[t & (PF - 1)];
    int tp = t + PF; if (tp > T_ - 1) tp = T_ - 1;
    pf[t & (PF - 1)] = emb[tp * K2_ + n];            // stays in flight (no barriers)

    // single-lane renorm reference: rcp/log overlap the FMA chain below
    float m   = rdlane(v, K2_ - 2);                  // v[50] > 0 always
    float inv = __builtin_amdgcn_rcpf(m);
    C += __builtin_amdgcn_logf(m);                   // v_log_f32 = log2

    float E = __builtin_amdgcn_exp2f(emv * LOG2E_);

    // y[n] = sum_p M2[n][p] * v[p]   (broadcast via v_readlane, 4 acc chains)
    float a0 = 0.0f, a1 = 0.0f, a2 = 0.0f, a3 = 0.0f;
#pragma unroll
    for (int p = 0; p < K2_; p += 4) {
      a0 = fmaf(M2[p + 0], rdlane(v, p + 0), a0);
      a1 = fmaf(M2[p + 1], rdlane(v, p + 1), a1);
      a2 = fmaf(M2[p + 2], rdlane(v, p + 2), a2);
      a3 = fmaf(M2[p + 3], rdlane(v, p + 3), a3);
    }
    float y = (a0 + a1) + (a2 + a3);

    v = y * inv * E;
  }

  // terminal: fwd = ln2 * (C + log2 sum_p v_p * 2^(tr2[STOP][p]))
  float stopv = (lane < K2_)
      ? v * __builtin_amdgcn_exp2f(tr[(K2_ - 1) * K2_ + n] * LOG2E_)
      : 0.0f;
#pragma unroll
  for (int off = 32; off >= 1; off >>= 1)
    stopv += __shfl_xor(stopv, off, 64);
  float fwd = (C + __builtin_amdgcn_logf(stopv)) * LN2_;

  // gold score (raw log domain)
  float gold = 0.0f;
  const int* labb = lab + b * T_;
  for (int t = lane; t < L; t += 64) {
    int l1 = labb[t];
    int l0 = (t == 0) ? (K2_ - 2) : labb[t - 1];
    gold += emb[t * K2_ + l1] + tr[l1 * K2_ + l0];
  }
  if (lane == 0) gold += tr[(K2_ - 1) * K2_ + labb[L - 1]];  // STOP <- last label
#pragma unroll
  for (int off = 32; off >= 1; off >>= 1)
    gold += __shfl_xor(gold, off, 64);

  if (lane == 0) per_b[b] = fwd - gold;
}

__global__ void reduce_mean_kernel(const float* __restrict__ per_b,
                                   float* __restrict__ out)
{
  const int tid = threadIdx.x;  // 256
  float v = per_b[tid];
#pragma unroll
  for (int off = 32; off >= 1; off >>= 1) v += __shfl_xor(v, off, 64);
  __shared__ float s[4];
  if ((tid & 63) == 0) s[tid >> 6] = v;
  __syncthreads();
  if (tid == 0) out[0] = ((s[0] + s[1]) + (s[2] + s[3])) * (1.0f / (float)B_);
}

extern "C" void kernel_launch(void* const* d_in, const int* in_sizes, int n_in,
                              void* d_out, int out_size, void* d_ws, size_t ws_size,
                              hipStream_t stream) {
  const float* em  = (const float*)d_in[0];   // [B,T,K2] f32
  const float* tr  = (const float*)d_in[1];   // [K2,K2]  f32
  const int*   len = (const int*)d_in[2];     // [B] i32
  const int*   lab = (const int*)d_in[3];     // [B,T] i32
  float* out = (float*)d_out;
  float* ws  = (float*)d_ws;                  // 256 floats of per-batch scores

  crf_fwd_kernel<<<B_, 64, 0, stream>>>(em, tr, len, lab, ws);
  reduce_mean_kernel<<<1, 256, 0, stream>>>(ws, out);
}

// Round 4
// 580.890 us; speedup vs baseline: 2.3760x; 2.3760x over previous
//
#include <hip/hip_runtime.h>

// CRF NLL forward loss. B=256, T=2048, K2=52 (50 labels + START=50 + STOP=51).
// Linear-domain forward recurrence, one wave per batch, no LDS, no barriers,
// single-lane renorm (lane 50 = START, always > 0):
//   v_{t+1}[n] = E_t[n] * (sum_p M2[n][p] v_t[p]) * rcp(v_t[50]),  C += log2(v_t[50])
// R3 failed because M2[52]/pf[] arrays were lowered to SCRATCH (VGPR_Count=40!).
// Here all per-step state is macro-generated named scalars -> guaranteed VGPRs.

#define B_    256
#define T_    2048
#define K2_   52
#define LOG2E_ 1.4426950408889634f
#define LN2_   0.6931471805599453f

__device__ __forceinline__ float rdlane(float v, int src) {
  return __uint_as_float(__builtin_amdgcn_readlane(__float_as_uint(v), src));
}

// F(i, c): i = prev-state index, c = accumulator chain (i % 4)
#define FORALL52(F) \
  F(0,0) F(1,1) F(2,2) F(3,3) F(4,0) F(5,1) F(6,2) F(7,3) \
  F(8,0) F(9,1) F(10,2) F(11,3) F(12,0) F(13,1) F(14,2) F(15,3) \
  F(16,0) F(17,1) F(18,2) F(19,3) F(20,0) F(21,1) F(22,2) F(23,3) \
  F(24,0) F(25,1) F(26,2) F(27,3) F(28,0) F(29,1) F(30,2) F(31,3) \
  F(32,0) F(33,1) F(34,2) F(35,3) F(36,0) F(37,1) F(38,2) F(39,3) \
  F(40,0) F(41,1) F(42,2) F(43,3) F(44,0) F(45,1) F(46,2) F(47,3) \
  F(48,0) F(49,1) F(50,2) F(51,3)

#define DECLM(i, c) float M_##i = __builtin_amdgcn_exp2f(tr[n * K2_ + i] * LOG2E_);
#define ACCF(i, c)  _a##c = fmaf(M_##i, rdlane(vv, i), _a##c);

// One forward step consuming emission register EV; refills EV from row NEWIDX.
#define STEP(EV, NEWIDX) do {                                   \
    float _ne  = emb[(NEWIDX) * K2_ + n];  /* prefetch, 4 steps of slack */ \
    float _m   = rdlane(vv, 50);                                \
    float _inv = __builtin_amdgcn_rcpf(_m);                     \
    C += __builtin_amdgcn_logf(_m);        /* v_log_f32 = log2 */ \
    float _E = __builtin_amdgcn_exp2f((EV) * LOG2E_);           \
    float _a0 = 0.0f, _a1 = 0.0f, _a2 = 0.0f, _a3 = 0.0f;       \
    FORALL52(ACCF)                                              \
    float _y = (_a0 + _a1) + (_a2 + _a3);                       \
    vv = _y * _inv * _E;                                        \
    EV = _ne;                                                   \
  } while (0)

__launch_bounds__(64, 1)
__global__ void crf_fwd_kernel(const float* __restrict__ em,
                               const float* __restrict__ tr,
                               const int*  __restrict__ len,
                               const int*  __restrict__ lab,
                               float* __restrict__ per_b)
{
  const int b    = blockIdx.x;
  const int lane = threadIdx.x;                      // 64
  const int n    = (lane < K2_) ? lane : (K2_ - 1);  // lanes 52..63 mirror lane 51
  const int L    = len[b];
  const float* emb = em + (size_t)b * (T_ * K2_);

  // Row n of exp2-transitions: 52 named scalars -> 52 physical VGPRs.
  FORALL52(DECLM)

  // linear-domain state; alpha = vv * 2^C.  vv starts as delta at START.
  float vv = (lane == 50) ? 1.0f : 0.0f;
  float C  = 0.0f;

  // emission prefetch ring: 4 named scalars, rotated by 4x-unrolled t-loop.
  float e0 = emb[0 * K2_ + n];
  float e1 = emb[1 * K2_ + n];
  float e2 = emb[2 * K2_ + n];
  float e3 = emb[3 * K2_ + n];

  int t = 0;
  for (; t + 4 <= L; t += 4) {
    int i4 = t + 4, i5 = t + 5, i6 = t + 6, i7 = t + 7;
    if (i4 > T_ - 1) i4 = T_ - 1;
    if (i5 > T_ - 1) i5 = T_ - 1;
    if (i6 > T_ - 1) i6 = T_ - 1;
    if (i7 > T_ - 1) i7 = T_ - 1;
    STEP(e0, i4);
    STEP(e1, i5);
    STEP(e2, i6);
    STEP(e3, i7);
  }
  int rem = L - t;                                   // 0..3
  if (rem > 0) STEP(e0, T_ - 1);
  if (rem > 1) STEP(e1, T_ - 1);
  if (rem > 2) STEP(e2, T_ - 1);

  // terminal: fwd = ln2 * (C + log2 sum_p vv_p * 2^(tr2[STOP][p]))
  float stopv = (lane < K2_)
      ? vv * __builtin_amdgcn_exp2f(tr[(K2_ - 1) * K2_ + n] * LOG2E_)
      : 0.0f;
#pragma unroll
  for (int off = 32; off >= 1; off >>= 1)
    stopv += __shfl_xor(stopv, off, 64);
  float fwd = (C + __builtin_amdgcn_logf(stopv)) * LN2_;

  // gold score (raw log domain)
  float gold = 0.0f;
  const int* labb = lab + b * T_;
  for (int tt = lane; tt < L; tt += 64) {
    int l1 = labb[tt];
    int l0 = (tt == 0) ? 50 : labb[tt - 1];
    gold += emb[tt * K2_ + l1] + tr[l1 * K2_ + l0];
  }
  if (lane == 0) gold += tr[(K2_ - 1) * K2_ + labb[L - 1]];  // STOP <- last label
#pragma unroll
  for (int off = 32; off >= 1; off >>= 1)
    gold += __shfl_xor(gold, off, 64);

  if (lane == 0) per_b[b] = fwd - gold;
}

__global__ void reduce_mean_kernel(const float* __restrict__ per_b,
                                   float* __restrict__ out)
{
  const int tid = threadIdx.x;  // 256
  float v = per_b[tid];
#pragma unroll
  for (int off = 32; off >= 1; off >>= 1) v += __shfl_xor(v, off, 64);
  __shared__ float s[4];
  if ((tid & 63) == 0) s[tid >> 6] = v;
  __syncthreads();
  if (tid == 0) out[0] = ((s[0] + s[1]) + (s[2] + s[3])) * (1.0f / (float)B_);
}

extern "C" void kernel_launch(void* const* d_in, const int* in_sizes, int n_in,
                              void* d_out, int out_size, void* d_ws, size_t ws_size,
                              hipStream_t stream) {
  const float* em  = (const float*)d_in[0];   // [B,T,K2] f32
  const float* tr  = (const float*)d_in[1];   // [K2,K2]  f32
  const int*   len = (const int*)d_in[2];     // [B] i32
  const int*   lab = (const int*)d_in[3];     // [B,T] i32
  float* out = (float*)d_out;
  float* ws  = (float*)d_ws;                  // 256 floats of per-batch scores

  crf_fwd_kernel<<<B_, 64, 0, stream>>>(em, tr, len, lab, ws);
  reduce_mean_kernel<<<1, 256, 0, stream>>>(ws, out);
}

// Round 5
// 508.342 us; speedup vs baseline: 2.7151x; 1.1427x over previous
//
#include <hip/hip_runtime.h>

// CRF NLL forward loss. B=256, T=2048, K2=52 (50 labels + START=50 + STOP=51).
// Linear-domain forward recurrence, one wave per batch, no LDS, no barriers.
//   v_{t+1}[n] = E_t[n] * (sum_p M2[n][p] v_t[p]),  renorm by v[50] every 4 steps.
// R4 lesson: named scalars stopped scratch, but the compiler REMATERIALIZED
// the 52 M-values inside the loop (VGPR_Count=44 -> not resident). Here the
// M values pass through asm volatile "+v" barriers -> opaque, must stay in VGPRs.

#define B_    256
#define T_    2048
#define K2_   52
#define LOG2E_ 1.4426950408889634f
#define LN2_   0.6931471805599453f

__device__ __forceinline__ float rdlane(float v, int src) {
  return __uint_as_float(__builtin_amdgcn_readlane(__float_as_uint(v), src));
}

// F(i, c): i = prev-state index, c = accumulator chain (i % 4)
#define FORALL52(F) \
  F(0,0) F(1,1) F(2,2) F(3,3) F(4,0) F(5,1) F(6,2) F(7,3) \
  F(8,0) F(9,1) F(10,2) F(11,3) F(12,0) F(13,1) F(14,2) F(15,3) \
  F(16,0) F(17,1) F(18,2) F(19,3) F(20,0) F(21,1) F(22,2) F(23,3) \
  F(24,0) F(25,1) F(26,2) F(27,3) F(28,0) F(29,1) F(30,2) F(31,3) \
  F(32,0) F(33,1) F(34,2) F(35,3) F(36,0) F(37,1) F(38,2) F(39,3) \
  F(40,0) F(41,1) F(42,2) F(43,3) F(48,0) F(49,1) F(50,2) F(51,3) \
  F(44,0) F(45,1) F(46,2) F(47,3)

#define DECLM(i, c) float M_##i = __builtin_amdgcn_exp2f(tr[n * K2_ + i] * LOG2E_);
#define ACCF(i, c)  _a##c = fmaf(M_##i, rdlane(vv, i), _a##c);

// Matvec core shared by both step flavors.
#define MATVEC(OUTY) \
    float _a0 = 0.0f, _a1 = 0.0f, _a2 = 0.0f, _a3 = 0.0f; \
    FORALL52(ACCF) \
    float OUTY = (_a0 + _a1) + (_a2 + _a3);

// Step WITH single-lane renorm (lane 50 = START, always > 0 after step 0).
#define STEP_R(EV, NEWIDX) do {                                 \
    float _ne  = emb[(NEWIDX) * K2_ + n];                       \
    float _m   = rdlane(vv, 50);                                \
    float _inv = __builtin_amdgcn_rcpf(_m);                     \
    C += __builtin_amdgcn_logf(_m);        /* v_log_f32 = log2 */ \
    float _E = __builtin_amdgcn_exp2f((EV) * LOG2E_);           \
    MATVEC(_y)                                                  \
    vv = _y * _inv * _E;                                        \
    EV = _ne;                                                   \
  } while (0)

// Step WITHOUT renorm (growth over <=4 unnormalized steps stays in fp32 range).
#define STEP_N(EV, NEWIDX) do {                                 \
    float _ne  = emb[(NEWIDX) * K2_ + n];                       \
    float _E = __builtin_amdgcn_exp2f((EV) * LOG2E_);           \
    MATVEC(_y)                                                  \
    vv = _y * _E;                                               \
    EV = _ne;                                                   \
  } while (0)

#define PIN(a,b,c,d,e,f,g,h,i,j,k,l,m) \
  asm volatile("" : "+v"(M_##a), "+v"(M_##b), "+v"(M_##c), "+v"(M_##d), \
                    "+v"(M_##e), "+v"(M_##f), "+v"(M_##g), "+v"(M_##h), \
                    "+v"(M_##i), "+v"(M_##j), "+v"(M_##k), "+v"(M_##l), \
                    "+v"(M_##m));

__launch_bounds__(64, 1)
__global__ void crf_fwd_kernel(const float* __restrict__ em,
                               const float* __restrict__ tr,
                               const int*  __restrict__ len,
                               const int*  __restrict__ lab,
                               float* __restrict__ per_b)
{
  const int b    = blockIdx.x;
  const int lane = threadIdx.x;                      // 64
  const int n    = (lane < K2_) ? lane : (K2_ - 1);  // lanes 52..63 mirror lane 51
  const int L    = len[b];
  const float* emb = em + (size_t)b * (T_ * K2_);

  // Row n of exp2-transitions: 52 named scalars, pinned opaque in VGPRs.
  FORALL52(DECLM)
  PIN( 0, 1, 2, 3, 4, 5, 6, 7, 8, 9,10,11,12)
  PIN(13,14,15,16,17,18,19,20,21,22,23,24,25)
  PIN(26,27,28,29,30,31,32,33,34,35,36,37,38)
  PIN(39,40,41,42,43,44,45,46,47,48,49,50,51)

  // linear-domain state; alpha = vv * 2^C.  vv starts as delta at START.
  float vv = (lane == 50) ? 1.0f : 0.0f;
  float C  = 0.0f;

  // emission prefetch ring: 4 named scalars, rotated by 4x-unrolled t-loop.
  float e0 = emb[0 * K2_ + n];
  float e1 = emb[1 * K2_ + n];
  float e2 = emb[2 * K2_ + n];
  float e3 = emb[3 * K2_ + n];

  int t = 0;
  for (; t + 4 <= L; t += 4) {
    int i4 = t + 4, i5 = t + 5, i6 = t + 6, i7 = t + 7;
    if (i4 > T_ - 1) i4 = T_ - 1;
    if (i5 > T_ - 1) i5 = T_ - 1;
    if (i6 > T_ - 1) i6 = T_ - 1;
    if (i7 > T_ - 1) i7 = T_ - 1;
    STEP_R(e0, i4);
    STEP_N(e1, i5);
    STEP_N(e2, i6);
    STEP_N(e3, i7);
  }
  int rem = L - t;                                   // 0..3
  if (rem > 0) STEP_R(e0, T_ - 1);
  if (rem > 1) STEP_N(e1, T_ - 1);
  if (rem > 2) STEP_N(e2, T_ - 1);

  // terminal: fwd = ln2 * (C + log2 sum_p vv_p * 2^(tr2[STOP][p]))
  float stopv = (lane < K2_)
      ? vv * __builtin_amdgcn_exp2f(tr[(K2_ - 1) * K2_ + n] * LOG2E_)
      : 0.0f;
#pragma unroll
  for (int off = 32; off >= 1; off >>= 1)
    stopv += __shfl_xor(stopv, off, 64);
  float fwd = (C + __builtin_amdgcn_logf(stopv)) * LN2_;

  // gold score (raw log domain)
  float gold = 0.0f;
  const int* labb = lab + b * T_;
  for (int tt = lane; tt < L; tt += 64) {
    int l1 = labb[tt];
    int l0 = (tt == 0) ? 50 : labb[tt - 1];
    gold += emb[tt * K2_ + l1] + tr[l1 * K2_ + l0];
  }
  if (lane == 0) gold += tr[(K2_ - 1) * K2_ + labb[L - 1]];  // STOP <- last label
#pragma unroll
  for (int off = 32; off >= 1; off >>= 1)
    gold += __shfl_xor(gold, off, 64);

  if (lane == 0) per_b[b] = fwd - gold;
}

__global__ void reduce_mean_kernel(const float* __restrict__ per_b,
                                   float* __restrict__ out)
{
  const int tid = threadIdx.x;  // 256
  float v = per_b[tid];
#pragma unroll
  for (int off = 32; off >= 1; off >>= 1) v += __shfl_xor(v, off, 64);
  __shared__ float s[4];
  if ((tid & 63) == 0) s[tid >> 6] = v;
  __syncthreads();
  if (tid == 0) out[0] = ((s[0] + s[1]) + (s[2] + s[3])) * (1.0f / (float)B_);
}

extern "C" void kernel_launch(void* const* d_in, const int* in_sizes, int n_in,
                              void* d_out, int out_size, void* d_ws, size_t ws_size,
                              hipStream_t stream) {
  const float* em  = (const float*)d_in[0];   // [B,T,K2] f32
  const float* tr  = (const float*)d_in[1];   // [K2,K2]  f32
  const int*   len = (const int*)d_in[2];     // [B] i32
  const int*   lab = (const int*)d_in[3];     // [B,T] i32
  float* out = (float*)d_out;
  float* ws  = (float*)d_ws;                  // 256 floats of per-batch scores

  crf_fwd_kernel<<<B_, 64, 0, stream>>>(em, tr, len, lab, ws);
  reduce_mean_kernel<<<1, 256, 0, stream>>>(ws, out);
}